// Round 14
// baseline (312.369 us; speedup 1.0000x reference)
//
#include <hip/hip_runtime.h>
#include <stdint.h>

// ---------- types ----------
typedef __attribute__((ext_vector_type(4))) float  f32x4;
typedef __attribute__((ext_vector_type(8))) short  short8;   // 8 bf16
typedef __attribute__((ext_vector_type(4))) short  short4v;  // 4 bf16

#define MFMA16(a,b,c) __builtin_amdgcn_mfma_f32_16x16x32_bf16((a),(b),(c),0,0,0)

static __device__ __forceinline__ unsigned short f2bf(float f) {
    unsigned int u = __float_as_uint(f);
    u += 0x7FFFu + ((u >> 16) & 1u);   // RNE
    return (unsigned short)(u >> 16);
}
static __device__ __forceinline__ float bflo(unsigned int v) { return __uint_as_float(v << 16); }
static __device__ __forceinline__ float bfhi(unsigned int v) { return __uint_as_float(v & 0xFFFF0000u); }
static __device__ __forceinline__ float bf2f(unsigned short v) { return __uint_as_float(((unsigned int)v) << 16); }
static __device__ __forceinline__ unsigned int packbf(float a, float b) {
    return (unsigned int)f2bf(a) | ((unsigned int)f2bf(b) << 16);
}

// B=2, S=2048, C=512, E=512, H=8, HD=64
// reshape(B,H,S,HD) w/o transpose => per (b,h): contiguous [2048][64] slab.

// =====================================================================
// Kernel 1: fused QKV projection (round-3 proven).
// =====================================================================
__global__ __launch_bounds__(256) void qkv_gemm(
    const float* __restrict__ x,
    const float* __restrict__ Wq, const float* __restrict__ bq,
    const float* __restrict__ Wk, const float* __restrict__ bk,
    const float* __restrict__ Wv, const float* __restrict__ bv,
    unsigned short* __restrict__ Qb, unsigned short* __restrict__ Kb,
    unsigned short* __restrict__ Vb)
{
    __shared__ unsigned short As[128 * 40];
    __shared__ unsigned short Bs[128 * 40];

    const int tid  = threadIdx.x;
    const int lane = tid & 63;
    const int wid  = tid >> 6;
    const int g = lane >> 4, c = lane & 15;
    const int wr = wid >> 1, wc = wid & 1;
    const int bm    = blockIdx.x;
    const int widx  = blockIdx.y >> 2;
    const int ntile = blockIdx.y & 3;

    const float* W    = (widx == 0) ? Wq : (widx == 1) ? Wk : Wv;
    const float* bias = (widx == 0) ? bq : (widx == 1) ? bk : bv;
    unsigned short* Y = (widx == 0) ? Qb : (widx == 1) ? Kb : Vb;
    const float* Abase = x + (size_t)bm * 128 * 512;
    const float* Bbase = W + (size_t)ntile * 128 * 512;

    f32x4 acc[4][4];
    #pragma unroll
    for (int m = 0; m < 4; m++)
        #pragma unroll
        for (int n = 0; n < 4; n++) acc[m][n] = (f32x4){0.f, 0.f, 0.f, 0.f};

    for (int kk = 0; kk < 512; kk += 32) {
        #pragma unroll
        for (int i = 0; i < 4; i++) {
            int f  = i * 256 + tid;
            int rr = f >> 3;
            int cc = (f & 7) * 4;
            f32x4 va = *(const f32x4*)(Abase + rr * 512 + kk + cc);
            f32x4 vb = *(const f32x4*)(Bbase + rr * 512 + kk + cc);
            short4v sa, sb;
            #pragma unroll
            for (int q = 0; q < 4; q++) { sa[q] = (short)f2bf(va[q]); sb[q] = (short)f2bf(vb[q]); }
            *(short4v*)(&As[rr * 40 + cc]) = sa;
            *(short4v*)(&Bs[rr * 40 + cc]) = sb;
        }
        __syncthreads();

        short8 af[4], bfr[4];
        #pragma unroll
        for (int m = 0; m < 4; m++) af[m]  = *(const short8*)(&As[(wr * 64 + m * 16 + c) * 40 + g * 8]);
        #pragma unroll
        for (int n = 0; n < 4; n++) bfr[n] = *(const short8*)(&Bs[(wc * 64 + n * 16 + c) * 40 + g * 8]);
        #pragma unroll
        for (int m = 0; m < 4; m++)
            #pragma unroll
            for (int n = 0; n < 4; n++)
                acc[m][n] = MFMA16(af[m], bfr[n], acc[m][n]);
        __syncthreads();
    }

    #pragma unroll
    for (int n = 0; n < 4; n++) {
        int colW = ntile * 128 + wc * 64 + n * 16 + c;
        float bb = bias[colW];
        #pragma unroll
        for (int m = 0; m < 4; m++) {
            #pragma unroll
            for (int r = 0; r < 4; r++) {
                int row = bm * 128 + wr * 64 + m * 16 + g * 4 + r;
                Y[(size_t)row * 512 + colW] = f2bf(acc[m][n][r] + bb);
            }
        }
    }
}

// =====================================================================
// Kernel 1.5: V transpose (unchanged).
// =====================================================================
__global__ __launch_bounds__(256) void v_transpose(
    const unsigned short* __restrict__ Vb, unsigned short* __restrict__ Vt)
{
    __shared__ unsigned short T[8][520];

    const int tid = threadIdx.x;
    const int t   = blockIdx.x;
    const int bh  = blockIdx.y;
    const int b = bh >> 3, h = bh & 7;

    #pragma unroll
    for (int i = 0; i < 2; i++) {
        int idx = i * 256 + tid;
        int j   = idx >> 6;
        int cc  = (idx & 63) * 8;
        short8 v = *(const short8*)(Vb + (size_t)(b * 2048 + h * 256 + t * 8 + j) * 512 + cc);
        *(short8*)(&T[j][cc]) = v;
    }
    __syncthreads();

    const int d   = tid >> 2;
    const int sjb = (tid & 3) * 16;
    unsigned short tmp[16];
    #pragma unroll
    for (int i = 0; i < 16; i++) {
        int sj = sjb + i;
        tmp[i] = T[sj >> 3][(sj & 7) * 64 + d];
    }
    unsigned short* dst = Vt + ((size_t)(bh * 64 + d) * 2048) + t * 64 + sjb;
    *(short8*)(dst)     = *(short8*)(&tmp[0]);
    *(short8*)(dst + 8) = *(short8*)(&tmp[8]);
}

// =====================================================================
// Kernel 2a: attn_core — phase 1 only. Computes e=exp2(z*SC) (masked->0),
// stores packed bf16 pairs as u32 to Pws in C-LAYOUT ORDER (so the store
// is exactly base + lane*4: 256B/instr, fully coalesced, zero conversion).
// Accumulates denom, stores 0.5/D per row to Dws.
// =====================================================================
__global__ __launch_bounds__(256) void attn_core(
    const unsigned short* __restrict__ Qb, const unsigned short* __restrict__ Kb,
    const int* __restrict__ mask,
    unsigned int* __restrict__ Pws, float* __restrict__ Dws)
{
    __shared__ float red[4][16];

    const int tid = threadIdx.x;
    const int lane = tid & 63, wid = tid >> 6;
    const int g = lane >> 4, c = lane & 15;

    const int wg  = blockIdx.x + gridDim.x * blockIdx.y;   // 0..2047
    const int qg  = (wg >> 3) & 127;
    const int bh  = (wg & 7) * 2 + ((wg >> 10) & 1);       // XCD-aware
    const int b = bh >> 3, h = bh & 7;

    const unsigned short* Qh = Qb + (size_t)b * 1048576 + (size_t)h * 131072;
    const unsigned short* Kh = Kb + (size_t)b * 1048576 + (size_t)h * 131072;
    const int* maskb = mask + b * 2048;

    const int qrow    = qg * 16;
    const int keybase = wid * 512;
    const float SC = 0.18033688011f;      // 0.125 / ln2

    short8 qf[2];
    #pragma unroll
    for (int ks = 0; ks < 2; ks++)
        qf[ks] = *(const short8*)(Qh + (size_t)(qrow + c) * 64 + ks * 32 + g * 8);

    unsigned int* Pw = Pws + ((((size_t)bh * 128 + qg) * 4 + wid) * 8) * 512 + lane;

    float dsum[4] = {0.f, 0.f, 0.f, 0.f};

    #pragma unroll
    for (int t = 0; t < 8; t++) {
        const int kb = keybase + t * 64;
        #pragma unroll
        for (int n = 0; n < 4; n++) {
            short8 k0 = *(const short8*)(Kh + (size_t)(kb + n * 16 + c) * 64 + g * 8);
            short8 k1 = *(const short8*)(Kh + (size_t)(kb + n * 16 + c) * 64 + 32 + g * 8);
            f32x4 z = (f32x4){0.f, 0.f, 0.f, 0.f};
            z = MFMA16(qf[0], k0, z);
            z = MFMA16(qf[1], k1, z);
            const int mv = maskb[kb + n * 16 + c];
            float e[4];
            #pragma unroll
            for (int r = 0; r < 4; r++) {
                float ex = exp2f(z[r] * SC);
                e[r] = mv ? 0.f : ex;
                dsum[r] += e[r];
            }
            Pw[(size_t)t * 512 + (n * 2 + 0) * 64] = packbf(e[0], e[1]);
            Pw[(size_t)t * 512 + (n * 2 + 1) * 64] = packbf(e[2], e[3]);
        }
    }
    #pragma unroll
    for (int r = 0; r < 4; r++) {
        #pragma unroll
        for (int off = 1; off < 16; off <<= 1)
            dsum[r] += __shfl_xor(dsum[r], off);
    }
    if (c == 0) {
        #pragma unroll
        for (int r = 0; r < 4; r++) red[wid][g * 4 + r] = dsum[r];
    }
    __syncthreads();
    if (tid < 16) {
        float D = red[0][tid] + red[1][tid] + red[2][tid] + red[3][tid];
        Dws[(size_t)bh * 2048 + qrow + tid] = 0.5f / D;   // folds blend 0.5
    }
}

// =====================================================================
// Kernel 2b: stream_pv — no QK^T, no exp. Loads packed e (coalesced),
// normalizes via Dws, blends with dist, stores attn (coalesced f32x4),
// PV MFMA via the AP LDS round-trip, cross-wave reduce, ctx store.
// Homogeneous streaming waves at low VGPR -> high occupancy.
// =====================================================================
__global__ __launch_bounds__(256) void stream_pv(
    const unsigned int* __restrict__ Pws, const float* __restrict__ Dws,
    const unsigned short* __restrict__ Vt, const float* __restrict__ dist,
    float* __restrict__ attn_out, unsigned short* __restrict__ ctx_bf)
{
    __shared__ __attribute__((aligned(16))) unsigned char SMEM[17408];
    unsigned short (*AP)[16][72] = (unsigned short (*)[16][72])SMEM;  // 4*2304B
    float (*Cred)[16][68] = (float (*)[16][68])SMEM;                  // 4*4352B

    const int tid = threadIdx.x;
    const int lane = tid & 63, wid = tid >> 6;
    const int g = lane >> 4, c = lane & 15;

    const int wg  = blockIdx.x + gridDim.x * blockIdx.y;   // 0..2047
    const int qg  = (wg >> 3) & 127;
    const int bh  = (wg & 7) * 2 + ((wg >> 10) & 1);       // XCD-aware
    const int b = bh >> 3, h = bh & 7;

    const unsigned short* Vth = Vt + (size_t)bh * 131072;  // [64 d][2048 s]
    const float* distb = dist + (size_t)bh * 4194304;
    float*       outb  = attn_out + (size_t)bh * 4194304;

    const int qrow    = qg * 16;
    const int keybase = wid * 512;

    float invd2[4];
    #pragma unroll
    for (int r = 0; r < 4; r++)
        invd2[r] = Dws[(size_t)bh * 2048 + qrow + g * 4 + r];

    const unsigned int* Pr = Pws + ((((size_t)bh * 128 + qg) * 4 + wid) * 8) * 512 + lane;

    f32x4 cacc[4];
    #pragma unroll
    for (int nd = 0; nd < 4; nd++) cacc[nd] = (f32x4){0.f, 0.f, 0.f, 0.f};

    #pragma unroll
    for (int t = 0; t < 8; t++) {
        const int kb = keybase + t * 64;

        // (a) packed-e loads (8 x 256B coalesced) + dist loads (4 x f32x4)
        unsigned int plv[8];
        #pragma unroll
        for (int j = 0; j < 8; j++) plv[j] = Pr[(size_t)t * 512 + j * 64];
        f32x4 dv[4];
        #pragma unroll
        for (int rg = 0; rg < 4; rg++)
            dv[rg] = *(const f32x4*)(distb + (size_t)(qrow + rg * 4 + g) * 2048 + kb + c * 4);

        // (b) 0.5*p -> AP in MFMA C-layout
        #pragma unroll
        for (int n = 0; n < 4; n++) {
            #pragma unroll
            for (int pi = 0; pi < 2; pi++) {
                unsigned int v = plv[n * 2 + pi];
                AP[wid][g * 4 + pi * 2    ][n * 16 + c] = f2bf(bflo(v) * invd2[pi * 2]);
                AP[wid][g * 4 + pi * 2 + 1][n * 16 + c] = f2bf(bfhi(v) * invd2[pi * 2 + 1]);
            }
        }

        // (c) streaming blend: ap = 0.5*p + 0.5*dist ; coalesced f32x4 store
        #pragma unroll
        for (int rg = 0; rg < 4; rg++) {
            const int row = rg * 4 + g;
            short4v pv = *(const short4v*)(&AP[wid][row][c * 4]);
            f32x4 apv;
            #pragma unroll
            for (int q = 0; q < 4; q++)
                apv[q] = fmaf(dv[rg][q], 0.5f, bf2f((unsigned short)pv[q]));
            *(f32x4*)(outb + (size_t)(qrow + row) * 2048 + kb + c * 4) = apv;
            short4v apb;
            #pragma unroll
            for (int q = 0; q < 4; q++) apb[q] = (short)f2bf(apv[q]);
            *(short4v*)(&AP[wid][row][c * 4]) = apb;
        }

        // (d) PV: A-frags of blended probs from LDS, V from L2
        short8 apf[2];
        #pragma unroll
        for (int ks = 0; ks < 2; ks++)
            apf[ks] = *(const short8*)(&AP[wid][c][ks * 32 + g * 8]);
        #pragma unroll
        for (int nd = 0; nd < 4; nd++) {
            #pragma unroll
            for (int ks = 0; ks < 2; ks++) {
                short8 vf = *(const short8*)(Vth + (size_t)(nd * 16 + c) * 2048 + kb + ks * 32 + g * 8);
                cacc[nd] = MFMA16(apf[ks], vf, cacc[nd]);
            }
        }
    }

    // ---------------- phase 4: cross-wave PV reduce (Cred aliases AP) ----------------
    __syncthreads();
    #pragma unroll
    for (int nd = 0; nd < 4; nd++)
        #pragma unroll
        for (int r = 0; r < 4; r++)
            Cred[wid][g * 4 + r][nd * 16 + c] = cacc[nd][r];
    __syncthreads();

    {
        const int q  = tid >> 4;          // 0..15
        const int dq = (tid & 15) * 4;    // 0..60
        f32x4 s = *(const f32x4*)(&Cred[0][q][dq]);
        #pragma unroll
        for (int w = 1; w < 4; w++) {
            f32x4 t2 = *(const f32x4*)(&Cred[w][q][dq]);
            #pragma unroll
            for (int j = 0; j < 4; j++) s[j] += t2[j];
        }
        short4v cb;
        #pragma unroll
        for (int j = 0; j < 4; j++) cb[j] = (short)f2bf(s[j]);
        *(short4v*)(ctx_bf + (size_t)(b * 2048 + qrow + q) * 512 + h * 64 + dq) = cb;
    }
}

// =====================================================================
// Kernel 2 (fallback, R12-proven): fused attention single kernel.
// Used when ws_size is too small for the split path.
// =====================================================================
__global__ __launch_bounds__(256) void attn_kernel(
    const unsigned short* __restrict__ Qb, const unsigned short* __restrict__ Kb,
    const unsigned short* __restrict__ Vt,
    const float* __restrict__ dist, const int* __restrict__ mask,
    float* __restrict__ attn_out, unsigned short* __restrict__ ctx_bf)
{
    __shared__ float red[4][16];
    __shared__ __attribute__((aligned(16))) unsigned char SMEM[17408];
    unsigned short (*AP)[16][72] = (unsigned short (*)[16][72])SMEM;
    float (*Cred)[16][68] = (float (*)[16][68])SMEM;

    const int tid = threadIdx.x;
    const int lane = tid & 63, wid = tid >> 6;
    const int g = lane >> 4, c = lane & 15;

    const int wg  = blockIdx.x + gridDim.x * blockIdx.y;
    const int qg  = (wg >> 3) & 127;
    const int bh  = (wg & 7) * 2 + ((wg >> 10) & 1);
    const int b = bh >> 3, h = bh & 7;

    const unsigned short* Qh  = Qb + (size_t)b * 1048576 + (size_t)h * 131072;
    const unsigned short* Kh  = Kb + (size_t)b * 1048576 + (size_t)h * 131072;
    const unsigned short* Vth = Vt + (size_t)bh * 131072;
    const float* distb = dist + (size_t)bh * 4194304;
    float*       outb  = attn_out + (size_t)bh * 4194304;
    const int*   maskb = mask + b * 2048;

    const int qrow    = qg * 16;
    const int keybase = wid * 512;
    const float SC = 0.18033688011f;

    short8 qf[2];
    #pragma unroll
    for (int ks = 0; ks < 2; ks++)
        qf[ks] = *(const short8*)(Qh + (size_t)(qrow + c) * 64 + ks * 32 + g * 8);

    unsigned int pl[8][4][2];
    float dsum[4] = {0.f, 0.f, 0.f, 0.f};

    #pragma unroll
    for (int t = 0; t < 8; t++) {
        const int kb = keybase + t * 64;
        #pragma unroll
        for (int n = 0; n < 4; n++) {
            short8 k0 = *(const short8*)(Kh + (size_t)(kb + n * 16 + c) * 64 + g * 8);
            short8 k1 = *(const short8*)(Kh + (size_t)(kb + n * 16 + c) * 64 + 32 + g * 8);
            f32x4 z = (f32x4){0.f, 0.f, 0.f, 0.f};
            z = MFMA16(qf[0], k0, z);
            z = MFMA16(qf[1], k1, z);
            const int mv = maskb[kb + n * 16 + c];
            float e[4];
            #pragma unroll
            for (int r = 0; r < 4; r++) {
                float ex = exp2f(z[r] * SC);
                e[r] = mv ? 0.f : ex;
                dsum[r] += e[r];
            }
            pl[t][n][0] = packbf(e[0], e[1]);
            pl[t][n][1] = packbf(e[2], e[3]);
        }
    }
    #pragma unroll
    for (int r = 0; r < 4; r++) {
        #pragma unroll
        for (int off = 1; off < 16; off <<= 1)
            dsum[r] += __shfl_xor(dsum[r], off);
    }
    if (c == 0) {
        #pragma unroll
        for (int r = 0; r < 4; r++) red[wid][g * 4 + r] = dsum[r];
    }
    __syncthreads();
    float invd2[4];
    #pragma unroll
    for (int r = 0; r < 4; r++) {
        const int row = g * 4 + r;
        invd2[r] = 0.5f / (red[0][row] + red[1][row] + red[2][row] + red[3][row]);
    }

    f32x4 cacc[4];
    #pragma unroll
    for (int nd = 0; nd < 4; nd++) cacc[nd] = (f32x4){0.f, 0.f, 0.f, 0.f};

    #pragma unroll
    for (int t = 0; t < 8; t++) {
        const int kb = keybase + t * 64;

        f32x4 dv[4];
        #pragma unroll
        for (int rg = 0; rg < 4; rg++)
            dv[rg] = *(const f32x4*)(distb + (size_t)(qrow + rg * 4 + g) * 2048 + kb + c * 4);

        #pragma unroll
        for (int n = 0; n < 4; n++) {
            #pragma unroll
            for (int pi = 0; pi < 2; pi++) {
                unsigned int v = pl[t][n][pi];
                AP[wid][g * 4 + pi * 2    ][n * 16 + c] = f2bf(bflo(v) * invd2[pi * 2]);
                AP[wid][g * 4 + pi * 2 + 1][n * 16 + c] = f2bf(bfhi(v) * invd2[pi * 2 + 1]);
            }
        }

        #pragma unroll
        for (int rg = 0; rg < 4; rg++) {
            const int row = rg * 4 + g;
            short4v pv = *(const short4v*)(&AP[wid][row][c * 4]);
            f32x4 apv;
            #pragma unroll
            for (int q = 0; q < 4; q++)
                apv[q] = fmaf(dv[rg][q], 0.5f, bf2f((unsigned short)pv[q]));
            *(f32x4*)(outb + (size_t)(qrow + row) * 2048 + kb + c * 4) = apv;
            short4v apb;
            #pragma unroll
            for (int q = 0; q < 4; q++) apb[q] = (short)f2bf(apv[q]);
            *(short4v*)(&AP[wid][row][c * 4]) = apb;
        }

        short8 apf[2];
        #pragma unroll
        for (int ks = 0; ks < 2; ks++)
            apf[ks] = *(const short8*)(&AP[wid][c][ks * 32 + g * 8]);
        #pragma unroll
        for (int nd = 0; nd < 4; nd++) {
            #pragma unroll
            for (int ks = 0; ks < 2; ks++) {
                short8 vf = *(const short8*)(Vth + (size_t)(nd * 16 + c) * 2048 + kb + ks * 32 + g * 8);
                cacc[nd] = MFMA16(apf[ks], vf, cacc[nd]);
            }
        }
    }

    __syncthreads();
    #pragma unroll
    for (int nd = 0; nd < 4; nd++)
        #pragma unroll
        for (int r = 0; r < 4; r++)
            Cred[wid][g * 4 + r][nd * 16 + c] = cacc[nd][r];
    __syncthreads();

    {
        const int q  = tid >> 4;
        const int dq = (tid & 15) * 4;
        f32x4 s = *(const f32x4*)(&Cred[0][q][dq]);
        #pragma unroll
        for (int w = 1; w < 4; w++) {
            f32x4 t2 = *(const f32x4*)(&Cred[w][q][dq]);
            #pragma unroll
            for (int j = 0; j < 4; j++) s[j] += t2[j];
        }
        short4v cb;
        #pragma unroll
        for (int j = 0; j < 4; j++) cb[j] = (short)f2bf(s[j]);
        *(short4v*)(ctx_bf + (size_t)(b * 2048 + qrow + q) * 512 + h * 64 + dq) = cb;
    }
}

// =====================================================================
// Kernel 3: out = ctx @ Wo^T + bo (unchanged).
// =====================================================================
__global__ __launch_bounds__(256) void out_gemm(
    const unsigned short* __restrict__ A,
    const float* __restrict__ Wo, const float* __restrict__ bo,
    float* __restrict__ out)
{
    __shared__ unsigned short As[128 * 40];
    __shared__ unsigned short Bs[128 * 40];

    const int tid  = threadIdx.x;
    const int lane = tid & 63;
    const int wid  = tid >> 6;
    const int g = lane >> 4, c = lane & 15;
    const int wr = wid >> 1, wc = wid & 1;
    const int bm    = blockIdx.x;
    const int ntile = blockIdx.y;

    const unsigned short* Abase = A + (size_t)bm * 128 * 512;
    const float* Bbase = Wo + (size_t)ntile * 128 * 512;

    f32x4 acc[4][4];
    #pragma unroll
    for (int m = 0; m < 4; m++)
        #pragma unroll
        for (int n = 0; n < 4; n++) acc[m][n] = (f32x4){0.f, 0.f, 0.f, 0.f};

    for (int kk = 0; kk < 512; kk += 32) {
        #pragma unroll
        for (int i = 0; i < 2; i++) {
            int f8 = i * 256 + tid;
            int rr = f8 >> 2;
            int cc = (f8 & 3) * 8;
            short8 va = *(const short8*)(Abase + (size_t)rr * 512 + kk + cc);
            *(short8*)(&As[rr * 40 + cc]) = va;
        }
        #pragma unroll
        for (int i = 0; i < 4; i++) {
            int f  = i * 256 + tid;
            int rr = f >> 3;
            int cc = (f & 7) * 4;
            f32x4 vb = *(const f32x4*)(Bbase + (size_t)rr * 512 + kk + cc);
            short4v sb;
            #pragma unroll
            for (int q = 0; q < 4; q++) sb[q] = (short)f2bf(vb[q]);
            *(short4v*)(&Bs[rr * 40 + cc]) = sb;
        }
        __syncthreads();

        short8 af[4], bfr[4];
        #pragma unroll
        for (int m = 0; m < 4; m++) af[m]  = *(const short8*)(&As[(wr * 64 + m * 16 + c) * 40 + g * 8]);
        #pragma unroll
        for (int n = 0; n < 4; n++) bfr[n] = *(const short8*)(&Bs[(wc * 64 + n * 16 + c) * 40 + g * 8]);
        #pragma unroll
        for (int m = 0; m < 4; m++)
            #pragma unroll
            for (int n = 0; n < 4; n++)
                acc[m][n] = MFMA16(af[m], bfr[n], acc[m][n]);
        __syncthreads();
    }

    #pragma unroll
    for (int n = 0; n < 4; n++) {
        int col = ntile * 128 + wc * 64 + n * 16 + c;
        float bb = bo[col];
        #pragma unroll
        for (int m = 0; m < 4; m++) {
            #pragma unroll
            for (int r = 0; r < 4; r++) {
                int row = bm * 128 + wr * 64 + m * 16 + g * 4 + r;
                out[(size_t)row * 512 + col] = acc[m][n][r] + bb;
            }
        }
    }
}

// =====================================================================
extern "C" void kernel_launch(void* const* d_in, const int* in_sizes, int n_in,
                              void* d_out, int out_size, void* d_ws, size_t ws_size,
                              hipStream_t stream)
{
    const float* x    = (const float*)d_in[0];
    const float* dist = (const float*)d_in[1];
    const int*   mask = (const int*)d_in[2];
    const float* Wq   = (const float*)d_in[3];
    const float* bq   = (const float*)d_in[4];
    const float* Wk   = (const float*)d_in[5];
    const float* bk   = (const float*)d_in[6];
    const float* Wv   = (const float*)d_in[7];
    const float* bv   = (const float*)d_in[8];
    const float* Wo   = (const float*)d_in[9];
    const float* bo   = (const float*)d_in[10];

    float* out      = (float*)d_out;            // (2,2048,512)
    float* attn_out = out + 2097152;            // (2,8,2048,2048)

    char* ws = (char*)d_ws;
    unsigned short* Qb  = (unsigned short*)(ws);                 // 4 MB
    unsigned short* Kb  = (unsigned short*)(ws + (4u << 20));    // 4 MB
    unsigned short* Vb  = (unsigned short*)(ws + (8u << 20));    // 4 MB (linear V)
    unsigned short* Vt  = (unsigned short*)(ws + (12u << 20));   // 4 MB [16][64][2048]
    unsigned short* ctx = (unsigned short*)(ws + (8u << 20));    // reuses Vb

    const size_t PW_OFF   = (size_t)16 << 20;                    // 16 MB
    const size_t PW_BYTES = (size_t)134217728;                   // 33.55M u32
    const size_t DW_OFF   = PW_OFF + PW_BYTES;
    const size_t NEED     = DW_OFF + (size_t)131072;             // ~151.1 MB

    qkv_gemm   <<<dim3(32, 12), 256, 0, stream>>>(x, Wq, bq, Wk, bk, Wv, bv, Qb, Kb, Vb);
    v_transpose<<<dim3(32, 16), 256, 0, stream>>>(Vb, Vt);

    if (ws_size >= NEED) {
        unsigned int* Pws = (unsigned int*)(ws + PW_OFF);
        float*        Dws = (float*)(ws + DW_OFF);
        attn_core <<<dim3(128, 16), 256, 0, stream>>>(Qb, Kb, mask, Pws, Dws);
        stream_pv <<<dim3(128, 16), 256, 0, stream>>>(Pws, Dws, Vt, dist, attn_out, ctx);
    } else {
        attn_kernel<<<dim3(128, 16), 256, 0, stream>>>(Qb, Kb, Vt, dist, mask, attn_out, ctx);
    }

    out_gemm   <<<dim3(32, 4),  256, 0, stream>>>(ctx, Wo, bo, out);
}

// Round 15
// 256.626 us; speedup vs baseline: 1.2172x; 1.2172x over previous
//
#include <hip/hip_runtime.h>
#include <stdint.h>

// ---------- types ----------
typedef __attribute__((ext_vector_type(4))) float  f32x4;
typedef __attribute__((ext_vector_type(8))) short  short8;   // 8 bf16
typedef __attribute__((ext_vector_type(4))) short  short4v;  // 4 bf16

#define MFMA16(a,b,c) __builtin_amdgcn_mfma_f32_16x16x32_bf16((a),(b),(c),0,0,0)

static __device__ __forceinline__ unsigned short f2bf(float f) {
    unsigned int u = __float_as_uint(f);
    u += 0x7FFFu + ((u >> 16) & 1u);   // RNE
    return (unsigned short)(u >> 16);
}
static __device__ __forceinline__ float bflo(unsigned int v) { return __uint_as_float(v << 16); }
static __device__ __forceinline__ float bfhi(unsigned int v) { return __uint_as_float(v & 0xFFFF0000u); }
static __device__ __forceinline__ float bf2f(unsigned short v) { return __uint_as_float(((unsigned int)v) << 16); }
static __device__ __forceinline__ unsigned int packbf(float a, float b) {
    return (unsigned int)f2bf(a) | ((unsigned int)f2bf(b) << 16);
}

// B=2, S=2048, C=512, E=512, H=8, HD=64
// reshape(B,H,S,HD) w/o transpose => per (b,h): contiguous [2048][64] slab.

// =====================================================================
// Kernel 1: fused QKV projection (round-3 proven).
// =====================================================================
__global__ __launch_bounds__(256) void qkv_gemm(
    const float* __restrict__ x,
    const float* __restrict__ Wq, const float* __restrict__ bq,
    const float* __restrict__ Wk, const float* __restrict__ bk,
    const float* __restrict__ Wv, const float* __restrict__ bv,
    unsigned short* __restrict__ Qb, unsigned short* __restrict__ Kb,
    unsigned short* __restrict__ Vb)
{
    __shared__ unsigned short As[128 * 40];
    __shared__ unsigned short Bs[128 * 40];

    const int tid  = threadIdx.x;
    const int lane = tid & 63;
    const int wid  = tid >> 6;
    const int g = lane >> 4, c = lane & 15;
    const int wr = wid >> 1, wc = wid & 1;
    const int bm    = blockIdx.x;
    const int widx  = blockIdx.y >> 2;
    const int ntile = blockIdx.y & 3;

    const float* W    = (widx == 0) ? Wq : (widx == 1) ? Wk : Wv;
    const float* bias = (widx == 0) ? bq : (widx == 1) ? bk : bv;
    unsigned short* Y = (widx == 0) ? Qb : (widx == 1) ? Kb : Vb;
    const float* Abase = x + (size_t)bm * 128 * 512;
    const float* Bbase = W + (size_t)ntile * 128 * 512;

    f32x4 acc[4][4];
    #pragma unroll
    for (int m = 0; m < 4; m++)
        #pragma unroll
        for (int n = 0; n < 4; n++) acc[m][n] = (f32x4){0.f, 0.f, 0.f, 0.f};

    for (int kk = 0; kk < 512; kk += 32) {
        #pragma unroll
        for (int i = 0; i < 4; i++) {
            int f  = i * 256 + tid;
            int rr = f >> 3;
            int cc = (f & 7) * 4;
            f32x4 va = *(const f32x4*)(Abase + rr * 512 + kk + cc);
            f32x4 vb = *(const f32x4*)(Bbase + rr * 512 + kk + cc);
            short4v sa, sb;
            #pragma unroll
            for (int q = 0; q < 4; q++) { sa[q] = (short)f2bf(va[q]); sb[q] = (short)f2bf(vb[q]); }
            *(short4v*)(&As[rr * 40 + cc]) = sa;
            *(short4v*)(&Bs[rr * 40 + cc]) = sb;
        }
        __syncthreads();

        short8 af[4], bfr[4];
        #pragma unroll
        for (int m = 0; m < 4; m++) af[m]  = *(const short8*)(&As[(wr * 64 + m * 16 + c) * 40 + g * 8]);
        #pragma unroll
        for (int n = 0; n < 4; n++) bfr[n] = *(const short8*)(&Bs[(wc * 64 + n * 16 + c) * 40 + g * 8]);
        #pragma unroll
        for (int m = 0; m < 4; m++)
            #pragma unroll
            for (int n = 0; n < 4; n++)
                acc[m][n] = MFMA16(af[m], bfr[n], acc[m][n]);
        __syncthreads();
    }

    #pragma unroll
    for (int n = 0; n < 4; n++) {
        int colW = ntile * 128 + wc * 64 + n * 16 + c;
        float bb = bias[colW];
        #pragma unroll
        for (int m = 0; m < 4; m++) {
            #pragma unroll
            for (int r = 0; r < 4; r++) {
                int row = bm * 128 + wr * 64 + m * 16 + g * 4 + r;
                Y[(size_t)row * 512 + colW] = f2bf(acc[m][n][r] + bb);
            }
        }
    }
}

// =====================================================================
// Kernel 1.5: V transpose (unchanged).
// =====================================================================
__global__ __launch_bounds__(256) void v_transpose(
    const unsigned short* __restrict__ Vb, unsigned short* __restrict__ Vt)
{
    __shared__ unsigned short T[8][520];

    const int tid = threadIdx.x;
    const int t   = blockIdx.x;
    const int bh  = blockIdx.y;
    const int b = bh >> 3, h = bh & 7;

    #pragma unroll
    for (int i = 0; i < 2; i++) {
        int idx = i * 256 + tid;
        int j   = idx >> 6;
        int cc  = (idx & 63) * 8;
        short8 v = *(const short8*)(Vb + (size_t)(b * 2048 + h * 256 + t * 8 + j) * 512 + cc);
        *(short8*)(&T[j][cc]) = v;
    }
    __syncthreads();

    const int d   = tid >> 2;
    const int sjb = (tid & 3) * 16;
    unsigned short tmp[16];
    #pragma unroll
    for (int i = 0; i < 16; i++) {
        int sj = sjb + i;
        tmp[i] = T[sj >> 3][(sj & 7) * 64 + d];
    }
    unsigned short* dst = Vt + ((size_t)(bh * 64 + d) * 2048) + t * 64 + sjb;
    *(short8*)(dst)     = *(short8*)(&tmp[0]);
    *(short8*)(dst + 8) = *(short8*)(&tmp[8]);
}

// =====================================================================
// Kernel 2: fused attention — R12 structure + PER-TILE DOUBLE-BUFFERED
// AP LDS. The single shared AP buffer was the last cross-tile memory
// dependence serializing the fully-unrolled tile loop: tile t+1's LDS
// writes could not be scheduled past tile t's LDS reads. AP[t&1][wid]
// gives adjacent tiles disjoint (compile-time constant) LDS ranges so
// the scheduler can overlap their full load->blend->store->PV chains.
// =====================================================================
__global__ __launch_bounds__(256) void attn_kernel(
    const unsigned short* __restrict__ Qb, const unsigned short* __restrict__ Kb,
    const unsigned short* __restrict__ Vt,
    const float* __restrict__ dist, const int* __restrict__ mask,
    float* __restrict__ attn_out, unsigned short* __restrict__ ctx_bf)
{
    __shared__ float red[4][16];                                  // 256 B
    __shared__ __attribute__((aligned(16))) unsigned char SMEM[18432];
    // phase 3: AP[2 bufs][4 waves][16 rows][72 cols] bf16 = 18432 B
    // phase 4: Cred[4][16][68] fp32 = 17408 B (aliases SMEM)
    unsigned short (*AP)[4][16][72] = (unsigned short (*)[4][16][72])SMEM;
    float (*Cred)[16][68] = (float (*)[16][68])SMEM;

    const int tid = threadIdx.x;
    const int lane = tid & 63, wid = tid >> 6;      // 4 waves
    const int g = lane >> 4, c = lane & 15;

    const int wg  = blockIdx.x + gridDim.x * blockIdx.y;   // 0..2047
    const int qg  = (wg >> 3) & 127;
    const int bh  = (wg & 7) * 2 + ((wg >> 10) & 1);       // XCD-aware
    const int b = bh >> 3, h = bh & 7;

    const unsigned short* Qh  = Qb + (size_t)b * 1048576 + (size_t)h * 131072;
    const unsigned short* Kh  = Kb + (size_t)b * 1048576 + (size_t)h * 131072;
    const unsigned short* Vth = Vt + (size_t)bh * 131072;       // [64 d][2048 s]
    const float* distb = dist + (size_t)bh * 4194304;
    float*       outb  = attn_out + (size_t)bh * 4194304;
    const int*   maskb = mask + b * 2048;

    const int qrow    = qg * 16;
    const int keybase = wid * 512;        // this wave's 512-key range

    const float SC = 0.18033688011f;      // 0.125 / ln2 (exp2 domain)

    short8 qf[2];
    #pragma unroll
    for (int ks = 0; ks < 2; ks++)
        qf[ks] = *(const short8*)(Qh + (size_t)(qrow + c) * 64 + ks * 32 + g * 8);

    // ---------------- phase 1: e = exp2(z*SC) (masked->0), denom ----------------
    unsigned int pl[8][4][2];             // packed bf16 unnormalized probs (64 VGPR)
    float dsum[4] = {0.f, 0.f, 0.f, 0.f};

    #pragma unroll
    for (int t = 0; t < 8; t++) {
        const int kb = keybase + t * 64;
        #pragma unroll
        for (int n = 0; n < 4; n++) {
            short8 k0 = *(const short8*)(Kh + (size_t)(kb + n * 16 + c) * 64 + g * 8);
            short8 k1 = *(const short8*)(Kh + (size_t)(kb + n * 16 + c) * 64 + 32 + g * 8);
            f32x4 z = (f32x4){0.f, 0.f, 0.f, 0.f};
            z = MFMA16(qf[0], k0, z);
            z = MFMA16(qf[1], k1, z);
            const int mv = maskb[kb + n * 16 + c];
            float e[4];
            #pragma unroll
            for (int r = 0; r < 4; r++) {
                float ex = exp2f(z[r] * SC);
                e[r] = mv ? 0.f : ex;
                dsum[r] += e[r];
            }
            pl[t][n][0] = packbf(e[0], e[1]);
            pl[t][n][1] = packbf(e[2], e[3]);
        }
    }
    #pragma unroll
    for (int r = 0; r < 4; r++) {
        #pragma unroll
        for (int off = 1; off < 16; off <<= 1)
            dsum[r] += __shfl_xor(dsum[r], off);
    }
    if (c == 0) {
        #pragma unroll
        for (int r = 0; r < 4; r++) red[wid][g * 4 + r] = dsum[r];
    }
    __syncthreads();
    float invd2[4];                       // 0.5 / denom (folds blend 0.5)
    #pragma unroll
    for (int r = 0; r < 4; r++) {
        const int row = g * 4 + r;
        invd2[r] = 0.5f / (red[0][row] + red[1][row] + red[2][row] + red[3][row]);
    }

    // ---------------- phase 3: p/2 -> AP(t&1), blend+store, PV ----------------
    f32x4 cacc[4];
    #pragma unroll
    for (int nd = 0; nd < 4; nd++) cacc[nd] = (f32x4){0.f, 0.f, 0.f, 0.f};

    #pragma unroll
    for (int t = 0; t < 8; t++) {
        const int kb = keybase + t * 64;
        unsigned short (*APt)[72] = AP[t & 1][wid];   // disjoint per parity

        // (a) dist loads first (4 x f32x4, 4 x 256B full-line segments)
        f32x4 dv[4];
        #pragma unroll
        for (int rg = 0; rg < 4; rg++)
            dv[rg] = *(const f32x4*)(distb + (size_t)(qrow + rg * 4 + g) * 2048 + kb + c * 4);

        // (b) 0.5*p -> APt in MFMA C-layout
        #pragma unroll
        for (int n = 0; n < 4; n++) {
            #pragma unroll
            for (int pi = 0; pi < 2; pi++) {
                unsigned int v = pl[t][n][pi];
                APt[g * 4 + pi * 2    ][n * 16 + c] = f2bf(bflo(v) * invd2[pi * 2]);
                APt[g * 4 + pi * 2 + 1][n * 16 + c] = f2bf(bfhi(v) * invd2[pi * 2 + 1]);
            }
        }

        // (c) streaming blend: ap = 0.5*p + 0.5*dist ; coalesced f32x4 store
        #pragma unroll
        for (int rg = 0; rg < 4; rg++) {
            const int row = rg * 4 + g;
            short4v pv = *(const short4v*)(&APt[row][c * 4]);
            f32x4 apv;
            #pragma unroll
            for (int q = 0; q < 4; q++)
                apv[q] = fmaf(dv[rg][q], 0.5f, bf2f((unsigned short)pv[q]));
            *(f32x4*)(outb + (size_t)(qrow + row) * 2048 + kb + c * 4) = apv;
            short4v apb;
            #pragma unroll
            for (int q = 0; q < 4; q++) apb[q] = (short)f2bf(apv[q]);
            *(short4v*)(&APt[row][c * 4]) = apb;
        }

        // (d) PV: A-frags of blended probs from APt, V from L2
        short8 apf[2];
        #pragma unroll
        for (int ks = 0; ks < 2; ks++)
            apf[ks] = *(const short8*)(&APt[c][ks * 32 + g * 8]);
        #pragma unroll
        for (int nd = 0; nd < 4; nd++) {
            #pragma unroll
            for (int ks = 0; ks < 2; ks++) {
                short8 vf = *(const short8*)(Vth + (size_t)(nd * 16 + c) * 2048 + kb + ks * 32 + g * 8);
                cacc[nd] = MFMA16(apf[ks], vf, cacc[nd]);
            }
        }
    }

    // ---------------- phase 4: cross-wave PV reduce (Cred aliases SMEM) ----------------
    __syncthreads();   // all AP reads done before Cred overwrites
    #pragma unroll
    for (int nd = 0; nd < 4; nd++)
        #pragma unroll
        for (int r = 0; r < 4; r++)
            Cred[wid][g * 4 + r][nd * 16 + c] = cacc[nd][r];
    __syncthreads();

    {
        const int q  = tid >> 4;          // 0..15
        const int dq = (tid & 15) * 4;    // 0..60
        f32x4 s = *(const f32x4*)(&Cred[0][q][dq]);
        #pragma unroll
        for (int w = 1; w < 4; w++) {
            f32x4 t2 = *(const f32x4*)(&Cred[w][q][dq]);
            #pragma unroll
            for (int j = 0; j < 4; j++) s[j] += t2[j];
        }
        short4v cb;
        #pragma unroll
        for (int j = 0; j < 4; j++) cb[j] = (short)f2bf(s[j]);
        *(short4v*)(ctx_bf + (size_t)(b * 2048 + qrow + q) * 512 + h * 64 + dq) = cb;
    }
}

// =====================================================================
// Kernel 3: out = ctx @ Wo^T + bo (unchanged).
// =====================================================================
__global__ __launch_bounds__(256) void out_gemm(
    const unsigned short* __restrict__ A,
    const float* __restrict__ Wo, const float* __restrict__ bo,
    float* __restrict__ out)
{
    __shared__ unsigned short As[128 * 40];
    __shared__ unsigned short Bs[128 * 40];

    const int tid  = threadIdx.x;
    const int lane = tid & 63;
    const int wid  = tid >> 6;
    const int g = lane >> 4, c = lane & 15;
    const int wr = wid >> 1, wc = wid & 1;
    const int bm    = blockIdx.x;
    const int ntile = blockIdx.y;

    const unsigned short* Abase = A + (size_t)bm * 128 * 512;
    const float* Bbase = Wo + (size_t)ntile * 128 * 512;

    f32x4 acc[4][4];
    #pragma unroll
    for (int m = 0; m < 4; m++)
        #pragma unroll
        for (int n = 0; n < 4; n++) acc[m][n] = (f32x4){0.f, 0.f, 0.f, 0.f};

    for (int kk = 0; kk < 512; kk += 32) {
        #pragma unroll
        for (int i = 0; i < 2; i++) {
            int f8 = i * 256 + tid;
            int rr = f8 >> 2;
            int cc = (f8 & 3) * 8;
            short8 va = *(const short8*)(Abase + (size_t)rr * 512 + kk + cc);
            *(short8*)(&As[rr * 40 + cc]) = va;
        }
        #pragma unroll
        for (int i = 0; i < 4; i++) {
            int f  = i * 256 + tid;
            int rr = f >> 3;
            int cc = (f & 7) * 4;
            f32x4 vb = *(const f32x4*)(Bbase + (size_t)rr * 512 + kk + cc);
            short4v sb;
            #pragma unroll
            for (int q = 0; q < 4; q++) sb[q] = (short)f2bf(vb[q]);
            *(short4v*)(&Bs[rr * 40 + cc]) = sb;
        }
        __syncthreads();

        short8 af[4], bfr[4];
        #pragma unroll
        for (int m = 0; m < 4; m++) af[m]  = *(const short8*)(&As[(wr * 64 + m * 16 + c) * 40 + g * 8]);
        #pragma unroll
        for (int n = 0; n < 4; n++) bfr[n] = *(const short8*)(&Bs[(wc * 64 + n * 16 + c) * 40 + g * 8]);
        #pragma unroll
        for (int m = 0; m < 4; m++)
            #pragma unroll
            for (int n = 0; n < 4; n++)
                acc[m][n] = MFMA16(af[m], bfr[n], acc[m][n]);
        __syncthreads();
    }

    #pragma unroll
    for (int n = 0; n < 4; n++) {
        int col = ntile * 128 + wc * 64 + n * 16 + c;
        float bb = bo[col];
        #pragma unroll
        for (int m = 0; m < 4; m++) {
            #pragma unroll
            for (int r = 0; r < 4; r++) {
                int row = bm * 128 + wr * 64 + m * 16 + g * 4 + r;
                out[(size_t)row * 512 + col] = acc[m][n][r] + bb;
            }
        }
    }
}

// =====================================================================
extern "C" void kernel_launch(void* const* d_in, const int* in_sizes, int n_in,
                              void* d_out, int out_size, void* d_ws, size_t ws_size,
                              hipStream_t stream)
{
    const float* x    = (const float*)d_in[0];
    const float* dist = (const float*)d_in[1];
    const int*   mask = (const int*)d_in[2];
    const float* Wq   = (const float*)d_in[3];
    const float* bq   = (const float*)d_in[4];
    const float* Wk   = (const float*)d_in[5];
    const float* bk   = (const float*)d_in[6];
    const float* Wv   = (const float*)d_in[7];
    const float* bv   = (const float*)d_in[8];
    const float* Wo   = (const float*)d_in[9];
    const float* bo   = (const float*)d_in[10];

    float* out      = (float*)d_out;            // (2,2048,512)
    float* attn_out = out + 2097152;            // (2,8,2048,2048)

    char* ws = (char*)d_ws;
    unsigned short* Qb  = (unsigned short*)(ws);                 // 4 MB
    unsigned short* Kb  = (unsigned short*)(ws + (4u << 20));    // 4 MB
    unsigned short* Vb  = (unsigned short*)(ws + (8u << 20));    // 4 MB (linear V)
    unsigned short* Vt  = (unsigned short*)(ws + (12u << 20));   // 4 MB [16][64][2048]
    unsigned short* ctx = (unsigned short*)(ws + (8u << 20));    // reuses Vb

    qkv_gemm   <<<dim3(32, 12), 256, 0, stream>>>(x, Wq, bq, Wk, bk, Wv, bv, Qb, Kb, Vb);
    v_transpose<<<dim3(32, 16), 256, 0, stream>>>(Vb, Vt);
    attn_kernel<<<dim3(128, 16), 256, 0, stream>>>(Qb, Kb, Vt, dist, mask, attn_out, ctx);
    out_gemm   <<<dim3(32, 4),  256, 0, stream>>>(ctx, Wo, bo, out);
}

// Round 16
// 242.398 us; speedup vs baseline: 1.2887x; 1.0587x over previous
//
#include <hip/hip_runtime.h>
#include <stdint.h>

// ---------- types ----------
typedef __attribute__((ext_vector_type(4))) float  f32x4;
typedef __attribute__((ext_vector_type(8))) short  short8;   // 8 bf16
typedef __attribute__((ext_vector_type(4))) short  short4v;  // 4 bf16

#define MFMA16(a,b,c) __builtin_amdgcn_mfma_f32_16x16x32_bf16((a),(b),(c),0,0,0)

static __device__ __forceinline__ unsigned short f2bf(float f) {
    unsigned int u = __float_as_uint(f);
    u += 0x7FFFu + ((u >> 16) & 1u);   // RNE
    return (unsigned short)(u >> 16);
}
static __device__ __forceinline__ float bflo(unsigned int v) { return __uint_as_float(v << 16); }
static __device__ __forceinline__ float bfhi(unsigned int v) { return __uint_as_float(v & 0xFFFF0000u); }
static __device__ __forceinline__ float bf2f(unsigned short v) { return __uint_as_float(((unsigned int)v) << 16); }
static __device__ __forceinline__ unsigned int packbf(float a, float b) {
    return (unsigned int)f2bf(a) | ((unsigned int)f2bf(b) << 16);
}

// B=2, S=2048, C=512, E=512, H=8, HD=64
// reshape(B,H,S,HD) w/o transpose => per (b,h): contiguous [2048][64] slab.

// =====================================================================
// Kernel 1: fused QKV projection (round-3 proven).
// =====================================================================
__global__ __launch_bounds__(256) void qkv_gemm(
    const float* __restrict__ x,
    const float* __restrict__ Wq, const float* __restrict__ bq,
    const float* __restrict__ Wk, const float* __restrict__ bk,
    const float* __restrict__ Wv, const float* __restrict__ bv,
    unsigned short* __restrict__ Qb, unsigned short* __restrict__ Kb,
    unsigned short* __restrict__ Vb)
{
    __shared__ unsigned short As[128 * 40];
    __shared__ unsigned short Bs[128 * 40];

    const int tid  = threadIdx.x;
    const int lane = tid & 63;
    const int wid  = tid >> 6;
    const int g = lane >> 4, c = lane & 15;
    const int wr = wid >> 1, wc = wid & 1;
    const int bm    = blockIdx.x;
    const int widx  = blockIdx.y >> 2;
    const int ntile = blockIdx.y & 3;

    const float* W    = (widx == 0) ? Wq : (widx == 1) ? Wk : Wv;
    const float* bias = (widx == 0) ? bq : (widx == 1) ? bk : bv;
    unsigned short* Y = (widx == 0) ? Qb : (widx == 1) ? Kb : Vb;
    const float* Abase = x + (size_t)bm * 128 * 512;
    const float* Bbase = W + (size_t)ntile * 128 * 512;

    f32x4 acc[4][4];
    #pragma unroll
    for (int m = 0; m < 4; m++)
        #pragma unroll
        for (int n = 0; n < 4; n++) acc[m][n] = (f32x4){0.f, 0.f, 0.f, 0.f};

    for (int kk = 0; kk < 512; kk += 32) {
        #pragma unroll
        for (int i = 0; i < 4; i++) {
            int f  = i * 256 + tid;
            int rr = f >> 3;
            int cc = (f & 7) * 4;
            f32x4 va = *(const f32x4*)(Abase + rr * 512 + kk + cc);
            f32x4 vb = *(const f32x4*)(Bbase + rr * 512 + kk + cc);
            short4v sa, sb;
            #pragma unroll
            for (int q = 0; q < 4; q++) { sa[q] = (short)f2bf(va[q]); sb[q] = (short)f2bf(vb[q]); }
            *(short4v*)(&As[rr * 40 + cc]) = sa;
            *(short4v*)(&Bs[rr * 40 + cc]) = sb;
        }
        __syncthreads();

        short8 af[4], bfr[4];
        #pragma unroll
        for (int m = 0; m < 4; m++) af[m]  = *(const short8*)(&As[(wr * 64 + m * 16 + c) * 40 + g * 8]);
        #pragma unroll
        for (int n = 0; n < 4; n++) bfr[n] = *(const short8*)(&Bs[(wc * 64 + n * 16 + c) * 40 + g * 8]);
        #pragma unroll
        for (int m = 0; m < 4; m++)
            #pragma unroll
            for (int n = 0; n < 4; n++)
                acc[m][n] = MFMA16(af[m], bfr[n], acc[m][n]);
        __syncthreads();
    }

    #pragma unroll
    for (int n = 0; n < 4; n++) {
        int colW = ntile * 128 + wc * 64 + n * 16 + c;
        float bb = bias[colW];
        #pragma unroll
        for (int m = 0; m < 4; m++) {
            #pragma unroll
            for (int r = 0; r < 4; r++) {
                int row = bm * 128 + wr * 64 + m * 16 + g * 4 + r;
                Y[(size_t)row * 512 + colW] = f2bf(acc[m][n][r] + bb);
            }
        }
    }
}

// =====================================================================
// Kernel 1.5: V transpose (unchanged).
// =====================================================================
__global__ __launch_bounds__(256) void v_transpose(
    const unsigned short* __restrict__ Vb, unsigned short* __restrict__ Vt)
{
    __shared__ unsigned short T[8][520];

    const int tid = threadIdx.x;
    const int t   = blockIdx.x;
    const int bh  = blockIdx.y;
    const int b = bh >> 3, h = bh & 7;

    #pragma unroll
    for (int i = 0; i < 2; i++) {
        int idx = i * 256 + tid;
        int j   = idx >> 6;
        int cc  = (idx & 63) * 8;
        short8 v = *(const short8*)(Vb + (size_t)(b * 2048 + h * 256 + t * 8 + j) * 512 + cc);
        *(short8*)(&T[j][cc]) = v;
    }
    __syncthreads();

    const int d   = tid >> 2;
    const int sjb = (tid & 3) * 16;
    unsigned short tmp[16];
    #pragma unroll
    for (int i = 0; i < 16; i++) {
        int sj = sjb + i;
        tmp[i] = T[sj >> 3][(sj & 7) * 64 + d];
    }
    unsigned short* dst = Vt + ((size_t)(bh * 64 + d) * 2048) + t * 64 + sjb;
    *(short8*)(dst)     = *(short8*)(&tmp[0]);
    *(short8*)(dst + 8) = *(short8*)(&tmp[8]);
}

// =====================================================================
// Kernel 2: fused attention — 8 waves x 256 keys (R8 champion) with a
// ROW-MAJOR stream phase:
//  (a) convert all 4 tiles' p -> per-wave LDS slab [16 rows][260] bf16
//      (tile t at cols t*64)
//  (b) stream 16 INDEPENDENT rows: dist load = 1024B contiguous
//      (lane l -> col l*4), blend from slab (512B contig read), attn
//      store = 1024B contiguous, bf16 write-back to slab
//  (c) PV per tile: A-frags from slab at [c][t*64+ks*32+g*8], V from L2
// This gives copy-kernel-like access: full-KB single-segment per
// instruction and 16-deep independent MLP per wave.
// =====================================================================
__global__ __launch_bounds__(512) void attn_kernel(
    const unsigned short* __restrict__ Qb, const unsigned short* __restrict__ Kb,
    const unsigned short* __restrict__ Vt,
    const float* __restrict__ dist, const int* __restrict__ mask,
    float* __restrict__ attn_out, unsigned short* __restrict__ ctx_bf)
{
    __shared__ float red[8][16];                                  // 512 B
    __shared__ __attribute__((aligned(16))) unsigned char SMEM[66560];
    // APs[8 waves][16 rows][260 cols] bf16 = 66560 B
    // Cred[8][16][68] fp32 = 34816 B (aliases SMEM in phase 4)
    unsigned short (*APs)[16][260] = (unsigned short (*)[16][260])SMEM;
    float (*Cred)[16][68] = (float (*)[16][68])SMEM;

    const int tid = threadIdx.x;
    const int lane = tid & 63, wid = tid >> 6;      // 8 waves
    const int g = lane >> 4, c = lane & 15;

    const int wg  = blockIdx.x + gridDim.x * blockIdx.y;   // 0..2047
    const int qg  = (wg >> 3) & 127;
    const int bh  = (wg & 7) * 2 + ((wg >> 10) & 1);       // XCD-aware
    const int b = bh >> 3, h = bh & 7;

    const unsigned short* Qh  = Qb + (size_t)b * 1048576 + (size_t)h * 131072;
    const unsigned short* Kh  = Kb + (size_t)b * 1048576 + (size_t)h * 131072;
    const unsigned short* Vth = Vt + (size_t)bh * 131072;       // [64 d][2048 s]
    const float* distb = dist + (size_t)bh * 4194304;
    float*       outb  = attn_out + (size_t)bh * 4194304;
    const int*   maskb = mask + b * 2048;

    const int qrow    = qg * 16;
    const int keybase = wid * 256;        // this wave's 256-key range

    const float SC = 0.18033688011f;      // 0.125 / ln2 (exp2 domain)

    short8 qf[2];
    #pragma unroll
    for (int ks = 0; ks < 2; ks++)
        qf[ks] = *(const short8*)(Qh + (size_t)(qrow + c) * 64 + ks * 32 + g * 8);

    // ---------------- phase 1: e = exp2(z*SC) (masked->0), denom ----------------
    unsigned int pl[4][4][2];             // packed bf16 unnormalized probs (32 VGPR)
    float dsum[4] = {0.f, 0.f, 0.f, 0.f};

    #pragma unroll
    for (int t = 0; t < 4; t++) {
        const int kb = keybase + t * 64;
        #pragma unroll
        for (int n = 0; n < 4; n++) {
            short8 k0 = *(const short8*)(Kh + (size_t)(kb + n * 16 + c) * 64 + g * 8);
            short8 k1 = *(const short8*)(Kh + (size_t)(kb + n * 16 + c) * 64 + 32 + g * 8);
            f32x4 z = (f32x4){0.f, 0.f, 0.f, 0.f};
            z = MFMA16(qf[0], k0, z);
            z = MFMA16(qf[1], k1, z);
            const int mv = maskb[kb + n * 16 + c];
            float e[4];
            #pragma unroll
            for (int r = 0; r < 4; r++) {
                float ex = exp2f(z[r] * SC);
                e[r] = mv ? 0.f : ex;
                dsum[r] += e[r];
            }
            pl[t][n][0] = packbf(e[0], e[1]);
            pl[t][n][1] = packbf(e[2], e[3]);
        }
    }
    #pragma unroll
    for (int r = 0; r < 4; r++) {
        #pragma unroll
        for (int off = 1; off < 16; off <<= 1)
            dsum[r] += __shfl_xor(dsum[r], off);
    }
    if (c == 0) {
        #pragma unroll
        for (int r = 0; r < 4; r++) red[wid][g * 4 + r] = dsum[r];
    }
    __syncthreads();
    float invd2[4];                       // 0.5 / denom (folds blend 0.5)
    #pragma unroll
    for (int r = 0; r < 4; r++) {
        const int row = g * 4 + r;
        float D = 0.f;
        #pragma unroll
        for (int w = 0; w < 8; w++) D += red[w][row];
        invd2[r] = 0.5f / D;
    }

    // ---------------- phase 3a: convert all 4 tiles' p -> slab ----------------
    #pragma unroll
    for (int t = 0; t < 4; t++) {
        #pragma unroll
        for (int n = 0; n < 4; n++) {
            #pragma unroll
            for (int pi = 0; pi < 2; pi++) {
                unsigned int v = pl[t][n][pi];
                APs[wid][g * 4 + pi * 2    ][t * 64 + n * 16 + c] = f2bf(bflo(v) * invd2[pi * 2]);
                APs[wid][g * 4 + pi * 2 + 1][t * 64 + n * 16 + c] = f2bf(bfhi(v) * invd2[pi * 2 + 1]);
            }
        }
    }

    // ---------------- phase 3b: row-major stream, 16 independent rows ----------------
    // lane l covers cols l*4..l*4+3 of each row: 1KB contiguous per instr.
    #pragma unroll
    for (int row = 0; row < 16; row++) {
        const float* dsrc = distb + (size_t)(qrow + row) * 2048 + keybase + lane * 4;
        f32x4 dv = *(const f32x4*)dsrc;
        short4v pv = *(const short4v*)(&APs[wid][row][lane * 4]);
        f32x4 apv;
        #pragma unroll
        for (int q = 0; q < 4; q++)
            apv[q] = fmaf(dv[q], 0.5f, bf2f((unsigned short)pv[q]));
        *(f32x4*)(outb + (size_t)(qrow + row) * 2048 + keybase + lane * 4) = apv;
        short4v apb;
        #pragma unroll
        for (int q = 0; q < 4; q++) apb[q] = (short)f2bf(apv[q]);
        *(short4v*)(&APs[wid][row][lane * 4]) = apb;
    }

    // ---------------- phase 3c: PV per tile (A-frags from slab, V from L2) ----------------
    f32x4 cacc[4];
    #pragma unroll
    for (int nd = 0; nd < 4; nd++) cacc[nd] = (f32x4){0.f, 0.f, 0.f, 0.f};

    #pragma unroll
    for (int t = 0; t < 4; t++) {
        const int kb = keybase + t * 64;
        short8 apf[2];
        #pragma unroll
        for (int ks = 0; ks < 2; ks++)
            apf[ks] = *(const short8*)(&APs[wid][c][t * 64 + ks * 32 + g * 8]);
        #pragma unroll
        for (int nd = 0; nd < 4; nd++) {
            #pragma unroll
            for (int ks = 0; ks < 2; ks++) {
                short8 vf = *(const short8*)(Vth + (size_t)(nd * 16 + c) * 2048 + kb + ks * 32 + g * 8);
                cacc[nd] = MFMA16(apf[ks], vf, cacc[nd]);
            }
        }
    }

    // ---------------- phase 4: cross-wave PV reduce (Cred aliases SMEM) ----------------
    __syncthreads();   // all APs reads done before Cred overwrites
    #pragma unroll
    for (int nd = 0; nd < 4; nd++)
        #pragma unroll
        for (int r = 0; r < 4; r++)
            Cred[wid][g * 4 + r][nd * 16 + c] = cacc[nd][r];
    __syncthreads();

    {
        const int q  = tid >> 5;          // 0..15
        const int d2 = (tid & 31) * 2;    // 0..62
        float s0 = 0.f, s1 = 0.f;
        #pragma unroll
        for (int w = 0; w < 8; w++) {
            s0 += Cred[w][q][d2];
            s1 += Cred[w][q][d2 + 1];
        }
        unsigned int pk = packbf(s0, s1);
        *(unsigned int*)(ctx_bf + (size_t)(b * 2048 + qrow + q) * 512 + h * 64 + d2) = pk;
    }
}

// =====================================================================
// Kernel 3: out = ctx @ Wo^T + bo (unchanged).
// =====================================================================
__global__ __launch_bounds__(256) void out_gemm(
    const unsigned short* __restrict__ A,
    const float* __restrict__ Wo, const float* __restrict__ bo,
    float* __restrict__ out)
{
    __shared__ unsigned short As[128 * 40];
    __shared__ unsigned short Bs[128 * 40];

    const int tid  = threadIdx.x;
    const int lane = tid & 63;
    const int wid  = tid >> 6;
    const int g = lane >> 4, c = lane & 15;
    const int wr = wid >> 1, wc = wid & 1;
    const int bm    = blockIdx.x;
    const int ntile = blockIdx.y;

    const unsigned short* Abase = A + (size_t)bm * 128 * 512;
    const float* Bbase = Wo + (size_t)ntile * 128 * 512;

    f32x4 acc[4][4];
    #pragma unroll
    for (int m = 0; m < 4; m++)
        #pragma unroll
        for (int n = 0; n < 4; n++) acc[m][n] = (f32x4){0.f, 0.f, 0.f, 0.f};

    for (int kk = 0; kk < 512; kk += 32) {
        #pragma unroll
        for (int i = 0; i < 2; i++) {
            int f8 = i * 256 + tid;
            int rr = f8 >> 2;
            int cc = (f8 & 3) * 8;
            short8 va = *(const short8*)(Abase + (size_t)rr * 512 + kk + cc);
            *(short8*)(&As[rr * 40 + cc]) = va;
        }
        #pragma unroll
        for (int i = 0; i < 4; i++) {
            int f  = i * 256 + tid;
            int rr = f >> 3;
            int cc = (f & 7) * 4;
            f32x4 vb = *(const f32x4*)(Bbase + (size_t)rr * 512 + kk + cc);
            short4v sb;
            #pragma unroll
            for (int q = 0; q < 4; q++) sb[q] = (short)f2bf(vb[q]);
            *(short4v*)(&Bs[rr * 40 + cc]) = sb;
        }
        __syncthreads();

        short8 af[4], bfr[4];
        #pragma unroll
        for (int m = 0; m < 4; m++) af[m]  = *(const short8*)(&As[(wr * 64 + m * 16 + c) * 40 + g * 8]);
        #pragma unroll
        for (int n = 0; n < 4; n++) bfr[n] = *(const short8*)(&Bs[(wc * 64 + n * 16 + c) * 40 + g * 8]);
        #pragma unroll
        for (int m = 0; m < 4; m++)
            #pragma unroll
            for (int n = 0; n < 4; n++)
                acc[m][n] = MFMA16(af[m], bfr[n], acc[m][n]);
        __syncthreads();
    }

    #pragma unroll
    for (int n = 0; n < 4; n++) {
        int col = ntile * 128 + wc * 64 + n * 16 + c;
        float bb = bo[col];
        #pragma unroll
        for (int m = 0; m < 4; m++) {
            #pragma unroll
            for (int r = 0; r < 4; r++) {
                int row = bm * 128 + wr * 64 + m * 16 + g * 4 + r;
                out[(size_t)row * 512 + col] = acc[m][n][r] + bb;
            }
        }
    }
}

// =====================================================================
extern "C" void kernel_launch(void* const* d_in, const int* in_sizes, int n_in,
                              void* d_out, int out_size, void* d_ws, size_t ws_size,
                              hipStream_t stream)
{
    const float* x    = (const float*)d_in[0];
    const float* dist = (const float*)d_in[1];
    const int*   mask = (const int*)d_in[2];
    const float* Wq   = (const float*)d_in[3];
    const float* bq   = (const float*)d_in[4];
    const float* Wk   = (const float*)d_in[5];
    const float* bk   = (const float*)d_in[6];
    const float* Wv   = (const float*)d_in[7];
    const float* bv   = (const float*)d_in[8];
    const float* Wo   = (const float*)d_in[9];
    const float* bo   = (const float*)d_in[10];

    float* out      = (float*)d_out;            // (2,2048,512)
    float* attn_out = out + 2097152;            // (2,8,2048,2048)

    char* ws = (char*)d_ws;
    unsigned short* Qb  = (unsigned short*)(ws);                 // 4 MB
    unsigned short* Kb  = (unsigned short*)(ws + (4u << 20));    // 4 MB
    unsigned short* Vb  = (unsigned short*)(ws + (8u << 20));    // 4 MB (linear V)
    unsigned short* Vt  = (unsigned short*)(ws + (12u << 20));   // 4 MB [16][64][2048]
    unsigned short* ctx = (unsigned short*)(ws + (8u << 20));    // reuses Vb

    qkv_gemm   <<<dim3(32, 12), 256, 0, stream>>>(x, Wq, bq, Wk, bk, Wv, bv, Qb, Kb, Vb);
    v_transpose<<<dim3(32, 16), 256, 0, stream>>>(Vb, Vt);
    attn_kernel<<<dim3(128, 16), 512, 0, stream>>>(Qb, Kb, Vt, dist, mask, attn_out, ctx);
    out_gemm   <<<dim3(32, 4),  256, 0, stream>>>(ctx, Wo, bo, out);
}